// Round 17
// baseline (172.182 us; speedup 1.0000x reference)
//
#include <hip/hip_runtime.h>

#define SCALE_EPS 1e-5f

typedef int v4i __attribute__((ext_vector_type(4)));
typedef int v16i __attribute__((ext_vector_type(16)));

static __device__ __forceinline__ void gll16(const void* g, void* l) {
  __builtin_amdgcn_global_load_lds(
      (const __attribute__((address_space(1))) unsigned int*)g,
      (__attribute__((address_space(3))) unsigned int*)l,
      16, 0, 0);
}

// Nibble-pair packed operand format (both A and B), biased u = q+8:
//   packed byte e of a 32x32 k-pair fragment: u[k] | u[k+32]<<4
//   fragment lane l = kh*32 + (row_or_col % 32); ds_read_b128 yields BOTH
//   ks=0 (lo nibbles) and ks=1 (hi nibbles) v4i MFMA operands.
// A tile (256 rows x 64 k, packed 8 KiB) at xq + (mt*64+kc)*8192
// B tile (256 cols x 64 k, packed 8 KiB) at wq + (nt*64+kc)*8192
// Bias removal: C = raw - 8*(sa_signed[t] + swU_biased[o])  (exact).

// ---------------------------------------------------------------------------
// Weight unpack: packed int32 [4096][2048] -> biased nibble-pair tiles.
// (unchanged from R15)
// ---------------------------------------------------------------------------
__global__ __launch_bounds__(256) void unpack_w(const int* __restrict__ wp,
                                                char* __restrict__ wq) {
  const int kc = blockIdx.x;   // 0..63
  const int nt2 = blockIdx.y;  // 0..15 (256-col tiles)
  const int tid = threadIdx.x;
  char* tile = wq + ((size_t)nt2 * 64 + kc) * 8192;
#pragma unroll
  for (int it = 0; it < 8; ++it) {
    int idx = it * 256 + tid;      // 0..2047
    int c = idx >> 3;              // col in tile 0..255
    int rem = idx & 7;
    int kh = rem >> 2, q = rem & 3;
    const int* src = wp + (size_t)(nt2 * 256 + c) * 2048 + kc * 32 + kh * 8 + q * 2;
    int i0 = src[0], i1 = src[1], j0 = src[16], j1 = src[17];
    unsigned dw = ((unsigned)i0 & 15) | (((unsigned)j0 & 15) << 4) |
                  ((((unsigned)i0 >> 4) & 15) << 8) | ((((unsigned)j0 >> 4) & 15) << 12) |
                  (((unsigned)i1 & 15) << 16) | (((unsigned)j1 & 15) << 20) |
                  ((((unsigned)i1 >> 4) & 15) << 24) | ((((unsigned)j1 >> 4) & 15) << 28);
    dw ^= 0x88888888u;  // raw nibble v -> v^8 = q+8 (biased)
    *(unsigned*)(tile + (c >> 5) * 1024 + (kh * 32 + (c & 31)) * 16 + q * 4) = dw;
  }
}

// ---------------------------------------------------------------------------
// Per-out-feature BIASED nibble sum: swU[o] = sum_k (q_w + 8). (unchanged)
// ---------------------------------------------------------------------------
__global__ __launch_bounds__(256) void sum_w(const int* __restrict__ wp,
                                             int* __restrict__ sw) {
  __shared__ int ls[4];
  const int row = blockIdx.x;
  const int tid = threadIdx.x;
  const v4i* src = (const v4i*)(wp + (size_t)row * 2048 + tid * 8);
  v4i m0 = src[0], m1 = src[1];
  int s = 0;
#pragma unroll
  for (int j = 0; j < 4; ++j) {
    int a = (j == 0) ? m0.x : (j == 1) ? m0.y : (j == 2) ? m0.z : m0.w;
    int b = (j == 0) ? m1.x : (j == 1) ? m1.y : (j == 2) ? m1.z : m1.w;
    s += ((a & 15) ^ 8) + (((a >> 4) & 15) ^ 8) + ((b & 15) ^ 8) + (((b >> 4) & 15) ^ 8);
  }
#pragma unroll
  for (int d = 1; d < 64; d <<= 1) s += __shfl_xor(s, d, 64);
  if ((tid & 63) == 0) ls[tid >> 6] = s;
  __syncthreads();
  if (tid == 0) sw[row] = ls[0] + ls[1] + ls[2] + ls[3];
}

// ---------------------------------------------------------------------------
// Activation quant (unchanged from R15).
// ---------------------------------------------------------------------------
__global__ __launch_bounds__(256) void quant_x(const float* __restrict__ x,
                                               char* __restrict__ xq,
                                               float* __restrict__ xs,
                                               int* __restrict__ sa) {
  __shared__ float lmax[4][4];
  __shared__ int lsum[4][4];
  const int tid = threadIdx.x;
  const int w = tid >> 6;        // wave -> 16 kc chunk
  const int l = tid & 63;
  const int t0 = blockIdx.x * 4;
  const int row = l >> 4;
  const int t = t0 + row;
  const int sub = l & 15;
  const int kcl = sub >> 3;      // which of 2 kc per s
  const int kh = (sub >> 2) & 1;
  const int j = sub & 3;

  float4 va[8], vb[8];
  float m = 0.0f;
#pragma unroll
  for (int s = 0; s < 8; ++s) {
    int kc = w * 16 + s * 2 + kcl;
    const float* p = x + (size_t)t * 4096 + kc * 64 + kh * 16 + j * 4;
    va[s] = *(const float4*)(p);
    vb[s] = *(const float4*)(p + 32);
    m = fmaxf(m, fmaxf(fmaxf(fabsf(va[s].x), fabsf(va[s].y)),
                       fmaxf(fabsf(va[s].z), fabsf(va[s].w))));
    m = fmaxf(m, fmaxf(fmaxf(fabsf(vb[s].x), fabsf(vb[s].y)),
                       fmaxf(fabsf(vb[s].z), fabsf(vb[s].w))));
  }
#pragma unroll
  for (int d = 1; d < 16; d <<= 1) m = fmaxf(m, __shfl_xor(m, d, 64));
  if (sub == 0) lmax[w][row] = m;
  __syncthreads();
  float rm = fmaxf(fmaxf(lmax[0][row], lmax[1][row]),
                   fmaxf(lmax[2][row], lmax[3][row]));
  float scale = fmaxf(rm / 7.0f, SCALE_EPS);
  if (w == 0 && sub == 0) xs[t] = scale;

  char* dst0 = xq + (size_t)(t >> 8) * 524288 + ((t & 255) >> 5) * 1024 +
               (kh * 32 + (t & 31)) * 16 + j * 4;

  int isum = 0;
#pragma unroll
  for (int s = 0; s < 8; ++s) {
    int kc = w * 16 + s * 2 + kcl;
    int q0 = (int)fminf(fmaxf(rintf(va[s].x / scale), -8.0f), 7.0f);
    int q1 = (int)fminf(fmaxf(rintf(va[s].y / scale), -8.0f), 7.0f);
    int q2 = (int)fminf(fmaxf(rintf(va[s].z / scale), -8.0f), 7.0f);
    int q3 = (int)fminf(fmaxf(rintf(va[s].w / scale), -8.0f), 7.0f);
    int q4 = (int)fminf(fmaxf(rintf(vb[s].x / scale), -8.0f), 7.0f);
    int q5 = (int)fminf(fmaxf(rintf(vb[s].y / scale), -8.0f), 7.0f);
    int q6 = (int)fminf(fmaxf(rintf(vb[s].z / scale), -8.0f), 7.0f);
    int q7 = (int)fminf(fmaxf(rintf(vb[s].w / scale), -8.0f), 7.0f);
    isum += q0 + q1 + q2 + q3 + q4 + q5 + q6 + q7;
    unsigned dw = (unsigned)((q0 + 8) | ((q4 + 8) << 4)) |
                  ((unsigned)((q1 + 8) | ((q5 + 8) << 4)) << 8) |
                  ((unsigned)((q2 + 8) | ((q6 + 8) << 4)) << 16) |
                  ((unsigned)((q3 + 8) | ((q7 + 8) << 4)) << 24);
    *(unsigned*)(dst0 + (size_t)kc * 8192) = dw;
  }
#pragma unroll
  for (int dd = 1; dd < 16; dd <<= 1) isum += __shfl_xor(isum, dd, 64);
  if (sub == 0) lsum[w][row] = isum;
  __syncthreads();
  if (w == 0 && sub == 0)
    sa[t] = lsum[0][row] + lsum[1][row] + lsum[2][row] + lsum[3][row];
}

// ---------------------------------------------------------------------------
// Packed-nibble GEMM, 256x256 tile, **16 waves (4Mx4N)**, BK=64,
// mfma_i32_32x32x32_i8. R16: TLP restructure — 4 waves/SIMD inside ONE block
// (launch_bounds(1024,4) -> 128-reg cap). Per-wave state shrunk to fit:
// acc[2][2]=64 AGPR, no cross-tile rotation, packed+unpacked operands
// ~32 VGPR (ks0 regs reused for ks1). Per tile per wave: 4 ds_read_b128 ->
// unpack ks0 -> 4 MFMA -> unpack ks1 -> 4 MFMA. Overlap of MFMA/VALU/LDS
// now comes from the 4-way wave parallelism per SIMD (m114), not from
// intra-wave scheduling (which R8-R15 showed serializes at 2 waves/SIMD:
// MfmaUtil+VALUBusy = 100%). One barrier + counted vmcnt(2) per K-tile;
// 1 gll16/thread/tile (A half: toff<8192, B half: toff>=8192).
// Producers and packed tile formats identical to R15 (proven correct).
// Epilogue: C = raw - 8*(sa + swU)  (exact).
// ---------------------------------------------------------------------------
__global__ __launch_bounds__(1024, 4) void gemm_i8(const char* __restrict__ xq,
                                                   const char* __restrict__ wq,
                                                   const float* __restrict__ xs,
                                                   const int* __restrict__ sa,
                                                   const int* __restrict__ sw,
                                                   const float* __restrict__ wsc,
                                                   float* __restrict__ out) {
  __shared__ char lds[4][16384];   // A packed 8K @0, B packed 8K @8192
  const int tid = threadIdx.x;
  const int wid = tid >> 6;        // 0..15
  const int lane = tid & 63;
  const int wm = wid >> 2;         // 0..3 : M quarter (64 rows)
  const int wn = wid & 3;          // 0..3 : N quarter (64 cols)

  // XCD-aware bijective swizzle (nwg = 512 = 8*64)
  const int bid = blockIdx.x;
  const int wg = (bid & 7) * 64 + (bid >> 3);
  const int by = wg >> 4;          // 0..31
  const int bx = wg & 15;          // 0..15

  const int toff = tid * 16;       // 0..16383 (one 16B unit of the 16K slot)
  // per-thread stage source: A half or B half of the K-tile (wave-uniform)
  const char* src = (toff < 8192)
      ? xq + (size_t)by * 524288 + toff
      : wq + (size_t)bx * 524288 + (toff - 8192);

  const int aro = wm * 2048 + lane * 16;          // A read base (rb=2wm)
  const int bro = 8192 + wn * 2048 + lane * 16;   // B read base (cf=2wn)

  v16i acc[2][2] = {};             // acc[rb][cf]

#define MFI(a, b, c) __builtin_amdgcn_mfma_i32_32x32x32_i8(a, b, c, 0, 0, 0)

#define TILE(kt, do_stage, vm)                                               \
  do {                                                                       \
    if ((vm) == 2) asm volatile("s_waitcnt vmcnt(2)" ::: "memory");          \
    else if ((vm) == 1) asm volatile("s_waitcnt vmcnt(1)" ::: "memory");     \
    else if ((vm) == 0) asm volatile("s_waitcnt vmcnt(0)" ::: "memory");     \
    __builtin_amdgcn_s_barrier();                                            \
    if (do_stage) {                                                          \
      gll16(src, lds[((kt) + 3) & 3] + toff);                                \
      src += 8192;                                                           \
    }                                                                        \
    const char* Ab_ = lds[(kt) & 3] + aro;                                   \
    const char* Bb_ = lds[(kt) & 3] + bro;                                   \
    v4i pA0 = *(const v4i*)(Ab_);                                            \
    v4i pA1 = *(const v4i*)(Ab_ + 1024);                                     \
    v4i pB0 = *(const v4i*)(Bb_);                                            \
    v4i pB1 = *(const v4i*)(Bb_ + 1024);                                     \
    v4i a0 = pA0 & M4, a1 = pA1 & M4;                                        \
    v4i b0 = pB0 & M4, b1 = pB1 & M4;                                        \
    __builtin_amdgcn_s_setprio(1);                                           \
    acc[0][0] = MFI(a0, b0, acc[0][0]);                                      \
    acc[0][1] = MFI(a0, b1, acc[0][1]);                                      \
    acc[1][0] = MFI(a1, b0, acc[1][0]);                                      \
    acc[1][1] = MFI(a1, b1, acc[1][1]);                                      \
    __builtin_amdgcn_s_setprio(0);                                           \
    a0 = (pA0 >> 4) & M4; a1 = (pA1 >> 4) & M4;                              \
    b0 = (pB0 >> 4) & M4; b1 = (pB1 >> 4) & M4;                              \
    __builtin_amdgcn_s_setprio(1);                                           \
    acc[0][0] = MFI(a0, b0, acc[0][0]);                                      \
    acc[0][1] = MFI(a0, b1, acc[0][1]);                                      \
    acc[1][0] = MFI(a1, b0, acc[1][0]);                                      \
    acc[1][1] = MFI(a1, b1, acc[1][1]);                                      \
    __builtin_amdgcn_s_setprio(0);                                           \
  } while (0)

  const v4i M4 = (v4i)(0x0f0f0f0f);

  // prologue: stage K-tiles 0,1,2 (3 loads/thread outstanding)
  gll16(src, lds[0] + toff); src += 8192;
  gll16(src, lds[1] + toff); src += 8192;
  gll16(src, lds[2] + toff); src += 8192;

  for (int kt = 0; kt < 61; ++kt) TILE(kt, 1, 2);  // kt=60 stages tile 63
  TILE(61, 0, 2);
  TILE(62, 0, 1);
  TILE(63, 0, 0);

#undef TILE
#undef MFI

  // epilogue: C/D 32x32: col = lane&31, row = (reg&3)+8*(reg>>2)+4*(lane>>5)
  const int colb = bx * 256 + wn * 64 + (lane & 31);
  int sw0 = sw[colb];
  int sw1 = sw[colb + 32];
  float wv0 = wsc[colb];
  float wv1 = wsc[colb + 32];
  const int rw = by * 256 + wm * 64 + ((lane >> 5) << 2);
#pragma unroll
  for (int rb = 0; rb < 2; ++rb) {
#pragma unroll
    for (int g = 0; g < 4; ++g) {
#pragma unroll
      for (int j = 0; j < 4; ++j) {
        int r = rw + rb * 32 + g * 8 + j;
        int reg = g * 4 + j;
        int sv = sa[r];
        float s = xs[r];
        float* orow = out + (size_t)r * 4096 + colb;
        orow[0]  = (float)(acc[rb][0][reg] - 8 * (sv + sw0)) * (s * wv0);
        orow[32] = (float)(acc[rb][1][reg] - 8 * (sv + sw1)) * (s * wv1);
      }
    }
  }
}

extern "C" void kernel_launch(void* const* d_in, const int* in_sizes, int n_in,
                              void* d_out, int out_size, void* d_ws, size_t ws_size,
                              hipStream_t stream) {
  const float* x = (const float*)d_in[0];
  const int* wp = (const int*)d_in[1];
  const float* wsc = (const float*)d_in[2];
  float* out = (float*)d_out;
  char* ws = (char*)d_ws;

  char* xq = ws;                                   // packed 8192*2048 = 16777216 B
  char* wq = ws + 16777216;                        // packed 4096*2048 =  8388608 B
  float* xs = (float*)(ws + 25165824);             // 8192*4
  int* sa = (int*)(ws + 25165824 + 32768);         // 8192*4
  int* sw = (int*)(ws + 25165824 + 65536);         // 4096*4

  hipLaunchKernelGGL(unpack_w, dim3(64, 16), dim3(256), 0, stream, wp, wq);
  hipLaunchKernelGGL(sum_w, dim3(4096), dim3(256), 0, stream, wp, sw);
  hipLaunchKernelGGL(quant_x, dim3(2048), dim3(256), 0, stream, x, xq, xs, sa);
  hipLaunchKernelGGL(gemm_i8, dim3(512), dim3(1024), 0, stream, xq, wq, xs, sa, sw, wsc, out);
}